// Round 3
// baseline (329.782 us; speedup 1.0000x reference)
//
#include <hip/hip_runtime.h>

// SFC model forward, bucket-binned for user_w gather locality.
//   out[b] = bias_w[0] + dot(user_w[user[b]], item_w[item[b]]) + freq_w[idx_emb[b], freq[b], 0]
// Round-1/2 rocprof: 512 MB of random 256B user_w gathers from HBM with zero
// reuse capture (expected unique footprint only ~225 MB). Counting-sort samples
// into buckets of 128 user rows (32 KB of user_w), then process buckets
// contiguously: duplicates hit L1/L2, unique fetches are semi-sequential.

#define EMB_DIM 64
#define NB 8192          // bucket slots (used: ceil(1e6/128) = 7813)
#define BUCKET_SHIFT 7   // 128 users/bucket -> 32 KB of user_w per bucket

__global__ void k_init(int* __restrict__ cnt, int* __restrict__ cursor) {
    int i = blockIdx.x * blockDim.x + threadIdx.x;
    if (i < NB) { cnt[i] = 0; cursor[i] = 0; }
}

__global__ void k_hist(const int* __restrict__ user, int* __restrict__ cnt, int B) {
    int i = blockIdx.x * blockDim.x + threadIdx.x;
    int stride = gridDim.x * blockDim.x;
    for (int s = i; s < B; s += stride)
        atomicAdd(&cnt[user[s] >> BUCKET_SHIFT], 1);
}

// exclusive prefix over NB counters: 1 block x 1024 threads, 8 counters/thread
__global__ __launch_bounds__(1024) void k_scan(const int* __restrict__ cnt,
                                               int* __restrict__ base) {
    __shared__ int part[1024];
    const int t = threadIdx.x;
    int loc[8];
    int sum = 0;
#pragma unroll
    for (int j = 0; j < 8; ++j) { loc[j] = cnt[t * 8 + j]; sum += loc[j]; }
    part[t] = sum;
    __syncthreads();
    for (int off = 1; off < 1024; off <<= 1) {   // Hillis-Steele inclusive
        int v = (t >= off) ? part[t - off] : 0;
        __syncthreads();
        part[t] += v;
        __syncthreads();
    }
    int excl = part[t] - sum;
#pragma unroll
    for (int j = 0; j < 8; ++j) { base[t * 8 + j] = excl; excl += loc[j]; }
}

__global__ void k_scatter(const int* __restrict__ user, const int* __restrict__ item,
                          const int* __restrict__ freq, const int* __restrict__ idx_emb,
                          const int* __restrict__ base, int* __restrict__ cursor,
                          int4* __restrict__ pairs, int B) {
    int i = blockIdx.x * blockDim.x + threadIdx.x;
    int stride = gridDim.x * blockDim.x;
    for (int s = i; s < B; s += stride) {
        const int u = user[s];
        const int b = u >> BUCKET_SHIFT;
        const int pos = atomicAdd(&cursor[b], 1);
        // pack: s (21b, B = 2^21) | freq (5b, <32) | idx_emb (6b, <50)
        const unsigned packed = (unsigned)s | ((unsigned)freq[s] << 21)
                              | ((unsigned)idx_emb[s] << 26);
        pairs[base[b] + pos] = make_int4(u, item[s], (int)packed, 0);
    }
}

__global__ __launch_bounds__(256) void k_main(
    const int4* __restrict__ pairs, const float* __restrict__ bias_w,
    const float* __restrict__ user_w, const float* __restrict__ item_w,
    const float* __restrict__ freq_w, float* __restrict__ out, int B, int nchunks)
{
    __shared__ int4 sp[256];
    // XCD swizzle: give each XCD a contiguous range of sorted chunks so
    // neighboring (same-bucket) chunks share that XCD's L2.
    const int b = blockIdx.x;
    const int chunk = ((nchunks & 7) == 0) ? ((b & 7) * (nchunks >> 3) + (b >> 3)) : b;
    const int tid = threadIdx.x;
    const int s0 = chunk * 256;
    {
        const int idx = s0 + tid;
        sp[tid] = (idx < B) ? pairs[idx] : make_int4(0, 0, 0, 0);
    }
    __syncthreads();
    const float bias0 = bias_w[0];   // zero[] is all-zeros; bias_w has 1 element
    const int g = tid >> 4, lane = tid & 15;

#pragma unroll
    for (int j = 0; j < 16; j += 2) {
        if (s0 + g * 16 + j >= B) break;             // group-uniform guard
        const int4 p0 = sp[g * 16 + j];
        const int4 p1 = sp[g * 16 + j + 1];
        const float4 u0 = *reinterpret_cast<const float4*>(user_w + (size_t)p0.x * EMB_DIM + lane * 4);
        const float4 v0 = *reinterpret_cast<const float4*>(item_w + (size_t)p0.y * EMB_DIM + lane * 4);
        const float4 u1 = *reinterpret_cast<const float4*>(user_w + (size_t)p1.x * EMB_DIM + lane * 4);
        const float4 v1 = *reinterpret_cast<const float4*>(item_w + (size_t)p1.y * EMB_DIM + lane * 4);
        float d0 = u0.x * v0.x + u0.y * v0.y + u0.z * v0.z + u0.w * v0.w;
        float d1 = u1.x * v1.x + u1.y * v1.y + u1.z * v1.z + u1.w * v1.w;
        d0 += __shfl_xor(d0, 1); d0 += __shfl_xor(d0, 2); d0 += __shfl_xor(d0, 4); d0 += __shfl_xor(d0, 8);
        d1 += __shfl_xor(d1, 1); d1 += __shfl_xor(d1, 2); d1 += __shfl_xor(d1, 4); d1 += __shfl_xor(d1, 8);
        if (lane == 0) {
            const unsigned q0 = (unsigned)p0.z, q1 = (unsigned)p1.z;
            const int sA = (int)(q0 & 0x1FFFFFu), sB = (int)(q1 & 0x1FFFFFu);
            const float fe0 = freq_w[((q0 >> 26) & 63u) * 32 + ((q0 >> 21) & 31u)];
            const float fe1 = freq_w[((q1 >> 26) & 63u) * 32 + ((q1 >> 21) & 31u)];
            const int last = s0 + g * 16 + j + 1;
            out[sA] = bias0 + d0 + fe0;
            if (last < B) out[sB] = bias0 + d1 + fe1;
        }
    }
}

// fallback: direct (round-1) kernel, used only if ws_size is too small
__global__ __launch_bounds__(256) void sfc_direct(
    const int* __restrict__ user, const int* __restrict__ item,
    const int* __restrict__ freq, const int* __restrict__ idx_emb,
    const int* __restrict__ zero, const float* __restrict__ bias_w,
    const float* __restrict__ user_w, const float* __restrict__ item_w,
    const float* __restrict__ freq_w, float* __restrict__ out, int B)
{
    const int group = threadIdx.x >> 4;
    const int lane = threadIdx.x & 15;
    const int stride = (gridDim.x * blockDim.x) >> 4;
    for (int s = blockIdx.x * 16 + group; s < B; s += stride) {
        const float4 uv = *reinterpret_cast<const float4*>(user_w + (size_t)user[s] * EMB_DIM + lane * 4);
        const float4 vv = *reinterpret_cast<const float4*>(item_w + (size_t)item[s] * EMB_DIM + lane * 4);
        float d = uv.x * vv.x + uv.y * vv.y + uv.z * vv.z + uv.w * vv.w;
        d += __shfl_xor(d, 1); d += __shfl_xor(d, 2); d += __shfl_xor(d, 4); d += __shfl_xor(d, 8);
        if (lane == 0)
            out[s] = bias_w[zero[s]] + d + freq_w[idx_emb[s] * 32 + freq[s]];
    }
}

extern "C" void kernel_launch(void* const* d_in, const int* in_sizes, int n_in,
                              void* d_out, int out_size, void* d_ws, size_t ws_size,
                              hipStream_t stream) {
    const int B = in_sizes[0];
    const int*   user    = (const int*)d_in[0];
    const int*   item    = (const int*)d_in[1];
    const int*   freq    = (const int*)d_in[2];
    const int*   idx_emb = (const int*)d_in[3];
    const int*   zero    = (const int*)d_in[4];
    const float* bias_w  = (const float*)d_in[5];
    const float* user_w  = (const float*)d_in[6];
    const float* item_w  = (const float*)d_in[7];
    const float* freq_w  = (const float*)d_in[8];
    float* out = (float*)d_out;

    // workspace layout
    char* w = (char*)d_ws;
    int*  cnt    = (int*)(w);
    int*  cursor = (int*)(w + 32 * 1024);
    int*  base   = (int*)(w + 64 * 1024);
    int4* pairs  = (int4*)(w + (1 << 20));
    const size_t need = (size_t)(1 << 20) + (size_t)B * sizeof(int4);

    if (ws_size < need) {
        sfc_direct<<<2048, 256, 0, stream>>>(user, item, freq, idx_emb, zero,
                                             bias_w, user_w, item_w, freq_w, out, B);
        return;
    }

    const int nchunks = (B + 255) / 256;
    k_init<<<(NB + 255) / 256, 256, 0, stream>>>(cnt, cursor);
    k_hist<<<1024, 256, 0, stream>>>(user, cnt, B);
    k_scan<<<1, 1024, 0, stream>>>(cnt, base);
    k_scatter<<<2048, 256, 0, stream>>>(user, item, freq, idx_emb, base, cursor, pairs, B);
    k_main<<<nchunks, 256, 0, stream>>>(pairs, bias_w, user_w, item_w, freq_w, out, B, nchunks);
}

// Round 4
// 263.685 us; speedup vs baseline: 1.2507x; 1.2507x over previous
//
#include <hip/hip_runtime.h>

// SFC model forward, L3-phased by user range.
//   out[b] = bias_w[0] + dot(user_w[user[b]], item_w[item[b]]) + freq_w[idx_emb[b], freq[b], 0]
//
// Round 1/2: direct gather = 553 MB FETCH at ~3.0 TB/s (random-256B ceiling),
// user_w (512 MB gathered, 221 MB unique) gets zero L3 reuse capture because
// the full 256 MB table + 26 MB item table exceed the 256 MB L3.
// Round 3: materialized binning cost 150 us of preprocessing -> net loss.
//
// This version: run TWO passes over the samples, pass p processing only
// samples with user id in [p*500K, (p+1)*500K). Per pass the user-row
// working set is ~110 MB unique rows -> fits L3 alongside item table, so the
// ~2x duplicate gathers become L3 hits. No sort, no atomics, no workspace.
// Cost: index arrays scanned twice (+32 MB), out lines touched twice (+8 MB).

#define EMB_DIM 64

__global__ __launch_bounds__(256) void sfc_pass(
    const int* __restrict__ user, const int* __restrict__ item,
    const int* __restrict__ freq, const int* __restrict__ idx_emb,
    const float* __restrict__ bias_w, const float* __restrict__ user_w,
    const float* __restrict__ item_w, const float* __restrict__ freq_w,
    float* __restrict__ out, int B, int lo, int hi)
{
    const int group  = threadIdx.x >> 4;   // 16 groups of 16 lanes per block
    const int lane   = threadIdx.x & 15;
    const int stride = (gridDim.x * blockDim.x) >> 4;
    const float bias0 = bias_w[0];         // zero[] is all-zeros, bias_w is [1]

    for (int s = blockIdx.x * 16 + group; s < B; s += stride) {
        const int u = user[s];             // broadcast load (all 16 lanes same addr)
        if (u >= lo && u < hi) {
            const float4 uv = *reinterpret_cast<const float4*>(
                user_w + (size_t)u * EMB_DIM + lane * 4);
            const float4 vv = *reinterpret_cast<const float4*>(
                item_w + (size_t)item[s] * EMB_DIM + lane * 4);
            float d = uv.x * vv.x + uv.y * vv.y + uv.z * vv.z + uv.w * vv.w;
            d += __shfl_xor(d, 1);
            d += __shfl_xor(d, 2);
            d += __shfl_xor(d, 4);
            d += __shfl_xor(d, 8);
            if (lane == 0) {
                out[s] = bias0 + d + freq_w[idx_emb[s] * 32 + freq[s]];
            }
        }
    }
}

extern "C" void kernel_launch(void* const* d_in, const int* in_sizes, int n_in,
                              void* d_out, int out_size, void* d_ws, size_t ws_size,
                              hipStream_t stream) {
    const int B = in_sizes[0];
    const int*   user    = (const int*)d_in[0];
    const int*   item    = (const int*)d_in[1];
    const int*   freq    = (const int*)d_in[2];
    const int*   idx_emb = (const int*)d_in[3];
    // d_in[4] (zero) intentionally unused: all zeros, bias_w has one element.
    const float* bias_w  = (const float*)d_in[5];
    const float* user_w  = (const float*)d_in[6];
    const float* item_w  = (const float*)d_in[7];
    const float* freq_w  = (const float*)d_in[8];
    float* out = (float*)d_out;

    const int num_users = in_sizes[6] / EMB_DIM;   // 1,000,000
    const int NPASS = 2;
    const int span = (num_users + NPASS - 1) / NPASS;

    for (int p = 0; p < NPASS; ++p) {
        const int lo = p * span;
        const int hi = (p == NPASS - 1) ? 0x7FFFFFFF : (p + 1) * span;
        sfc_pass<<<2048, 256, 0, stream>>>(user, item, freq, idx_emb,
                                           bias_w, user_w, item_w, freq_w,
                                           out, B, lo, hi);
    }
}

// Round 5
// 249.062 us; speedup vs baseline: 1.3241x; 1.0587x over previous
//
#include <hip/hip_runtime.h>

// SFC model forward, two-phase counting-sort partition + L2-local gather.
//   out[b] = bias_w[0] + dot(user_w[user[b]], item_w[item[b]]) + freq_w[idx_emb[b], freq[b], 0]
//
// Evidence so far: random 256B gathers cap at ~3.0-3.4 TB/s regardless of
// structure; L3 does not capture random reuse; only per-XCD L2 can. Round-2's
// sorted main kernel worked but its atomic+scatter preprocessing cost 150us.
// This round: atomic-free two-phase counting sort (LDS histograms -> scan ->
// LDS-cursor scatter), buckets of 2048 users (512KB of user_w), then the main
// kernel walks sorted samples with XCD-chunked block swizzle so each XCD's L2
// holds the active bucket's user rows (dup capture) and compulsory misses are
// semi-sequential.

#define EMB_DIM 64
#define NBKT 512           // buckets: user >> 11 -> 489 used
#define BSHIFT 11
#define GHIST 128          // blocks in hist/scatter phases

// ---- phase A: per-block histogram over its contiguous sample segment ----
__global__ __launch_bounds__(256) void k_hist(const int* __restrict__ user,
                                              int* __restrict__ hist, int B) {
    __shared__ int h[NBKT];
    for (int i = threadIdx.x; i < NBKT; i += 256) h[i] = 0;
    __syncthreads();
    const int seg = B / GHIST;                 // 16384
    const int s0 = blockIdx.x * seg;
    for (int k = threadIdx.x; k < seg; k += 256)
        atomicAdd(&h[user[s0 + k] >> BSHIFT], 1);
    __syncthreads();
    for (int i = threadIdx.x; i < NBKT; i += 256)
        hist[blockIdx.x * NBKT + i] = h[i];
}

// ---- phase B: global exclusive bases, one block of 512 threads ----
__global__ __launch_bounds__(512) void k_scan(const int* __restrict__ hist,
                                              int* __restrict__ base) {
    __shared__ int tot[NBKT];
    const int b = threadIdx.x;                 // bucket id
    int t = 0;
    for (int g = 0; g < GHIST; ++g) t += hist[g * NBKT + b];
    tot[b] = t;
    __syncthreads();
    // Hillis-Steele inclusive scan over 512 bucket totals
    for (int off = 1; off < NBKT; off <<= 1) {
        int v = (b >= off) ? tot[b - off] : 0;
        __syncthreads();
        tot[b] += v;
        __syncthreads();
    }
    int run = tot[b] - t;                      // exclusive bucket base
    for (int g = 0; g < GHIST; ++g) {
        base[g * NBKT + b] = run;
        run += hist[g * NBKT + b];
    }
}

// ---- phase C: scatter packed samples to sorted positions (LDS cursors) ----
__global__ __launch_bounds__(256) void k_scatter(
    const int* __restrict__ user, const int* __restrict__ item,
    const int* __restrict__ freq, const int* __restrict__ idx_emb,
    const int* __restrict__ base, int4* __restrict__ pairs, int B) {
    __shared__ int cur[NBKT];
    for (int i = threadIdx.x; i < NBKT; i += 256)
        cur[i] = base[blockIdx.x * NBKT + i];
    __syncthreads();
    const int seg = B / GHIST;
    const int s0 = blockIdx.x * seg;
    for (int k = threadIdx.x; k < seg; k += 256) {
        const int s = s0 + k;
        const int u = user[s];
        const unsigned packed = (unsigned)s | ((unsigned)freq[s] << 21)
                              | ((unsigned)idx_emb[s] << 26);
        const int pos = atomicAdd(&cur[u >> BSHIFT], 1);
        pairs[pos] = make_int4(u, item[s], (int)packed, 0);
    }
}

// ---- phase D: main gather/dot over sorted samples ----
__global__ __launch_bounds__(256) void k_main(
    const int4* __restrict__ pairs, const float* __restrict__ bias_w,
    const float* __restrict__ user_w, const float* __restrict__ item_w,
    const float* __restrict__ freq_w, float* __restrict__ out, int nchunks)
{
    __shared__ int4 sp[256];
    // XCD-chunked swizzle: XCD x (= blockIdx%8 by dispatch round-robin)
    // processes the contiguous chunk range [x*n/8, (x+1)*n/8).
    const int b = blockIdx.x;
    const int chunk = (b & 7) * (nchunks >> 3) + (b >> 3);
    const int tid = threadIdx.x;
    const int s0 = chunk * 256;
    sp[tid] = pairs[s0 + tid];
    __syncthreads();
    const float bias0 = bias_w[0];             // zero[] is all-zeros, bias_w is [1]
    const int g = tid >> 4, lane = tid & 15;

#pragma unroll
    for (int j = 0; j < 16; j += 2) {
        const int4 p0 = sp[g * 16 + j];
        const int4 p1 = sp[g * 16 + j + 1];
        const float4 u0 = *reinterpret_cast<const float4*>(user_w + (size_t)p0.x * EMB_DIM + lane * 4);
        const float4 v0 = *reinterpret_cast<const float4*>(item_w + (size_t)p0.y * EMB_DIM + lane * 4);
        const float4 u1 = *reinterpret_cast<const float4*>(user_w + (size_t)p1.x * EMB_DIM + lane * 4);
        const float4 v1 = *reinterpret_cast<const float4*>(item_w + (size_t)p1.y * EMB_DIM + lane * 4);
        float d0 = u0.x * v0.x + u0.y * v0.y + u0.z * v0.z + u0.w * v0.w;
        float d1 = u1.x * v1.x + u1.y * v1.y + u1.z * v1.z + u1.w * v1.w;
        d0 += __shfl_xor(d0, 1); d0 += __shfl_xor(d0, 2); d0 += __shfl_xor(d0, 4); d0 += __shfl_xor(d0, 8);
        d1 += __shfl_xor(d1, 1); d1 += __shfl_xor(d1, 2); d1 += __shfl_xor(d1, 4); d1 += __shfl_xor(d1, 8);
        if (lane == 0) {
            const unsigned q0 = (unsigned)p0.z, q1 = (unsigned)p1.z;
            out[q0 & 0x1FFFFFu] = bias0 + d0 + freq_w[((q0 >> 26) & 63u) * 32 + ((q0 >> 21) & 31u)];
            out[q1 & 0x1FFFFFu] = bias0 + d1 + freq_w[((q1 >> 26) & 63u) * 32 + ((q1 >> 21) & 31u)];
        }
    }
}

// ---- fallback: round-1 direct kernel (used only if workspace too small) ----
__global__ __launch_bounds__(256) void sfc_direct(
    const int* __restrict__ user, const int* __restrict__ item,
    const int* __restrict__ freq, const int* __restrict__ idx_emb,
    const float* __restrict__ bias_w, const float* __restrict__ user_w,
    const float* __restrict__ item_w, const float* __restrict__ freq_w,
    float* __restrict__ out, int B)
{
    const int group = threadIdx.x >> 4;
    const int lane = threadIdx.x & 15;
    const int stride = (gridDim.x * blockDim.x) >> 4;
    const float bias0 = bias_w[0];
    for (int s = blockIdx.x * 16 + group; s < B; s += stride) {
        const float4 uv = *reinterpret_cast<const float4*>(user_w + (size_t)user[s] * EMB_DIM + lane * 4);
        const float4 vv = *reinterpret_cast<const float4*>(item_w + (size_t)item[s] * EMB_DIM + lane * 4);
        float d = uv.x * vv.x + uv.y * vv.y + uv.z * vv.z + uv.w * vv.w;
        d += __shfl_xor(d, 1); d += __shfl_xor(d, 2); d += __shfl_xor(d, 4); d += __shfl_xor(d, 8);
        if (lane == 0)
            out[s] = bias0 + d + freq_w[idx_emb[s] * 32 + freq[s]];
    }
}

extern "C" void kernel_launch(void* const* d_in, const int* in_sizes, int n_in,
                              void* d_out, int out_size, void* d_ws, size_t ws_size,
                              hipStream_t stream) {
    const int B = in_sizes[0];
    const int*   user    = (const int*)d_in[0];
    const int*   item    = (const int*)d_in[1];
    const int*   freq    = (const int*)d_in[2];
    const int*   idx_emb = (const int*)d_in[3];
    // d_in[4] (zero) unused: all zeros, bias_w has one element.
    const float* bias_w  = (const float*)d_in[5];
    const float* user_w  = (const float*)d_in[6];
    const float* item_w  = (const float*)d_in[7];
    const float* freq_w  = (const float*)d_in[8];
    float* out = (float*)d_out;

    // workspace layout: [hist 256KB][base 256KB][pad to 1MB][pairs 32MB]
    char* w = (char*)d_ws;
    int*  hist  = (int*)(w);
    int*  base  = (int*)(w + NBKT * GHIST * sizeof(int));
    int4* pairs = (int4*)(w + (1 << 20));
    const size_t need = (size_t)(1 << 20) + (size_t)B * sizeof(int4);

    if (ws_size < need || (B % (GHIST * 256)) != 0) {
        sfc_direct<<<2048, 256, 0, stream>>>(user, item, freq, idx_emb,
                                             bias_w, user_w, item_w, freq_w, out, B);
        return;
    }

    const int nchunks = B / 256;   // 8192, divisible by 8
    k_hist   <<<GHIST, 256, 0, stream>>>(user, hist, B);
    k_scan   <<<1, NBKT, 0, stream>>>(hist, base);
    k_scatter<<<GHIST, 256, 0, stream>>>(user, item, freq, idx_emb, base, pairs, B);
    k_main   <<<nchunks, 256, 0, stream>>>(pairs, bias_w, user_w, item_w, freq_w, out, nchunks);
}

// Round 7
// 165.847 us; speedup vs baseline: 1.9885x; 1.5018x over previous
//
#include <hip/hip_runtime.h>

// SFC model forward — direct gather at the random-line-rate ceiling.
//   out[b] = bias_w[0] + dot(user_w[user[b]], item_w[item[b]]) + freq_w[idx_emb[b], freq[b], 0]
//
// Evidence from rounds 1-5: every structure (random, bucket-sorted, range-
// masked) serves this gather mix at ~3.0-3.1 TB/s == ~26G cache-lines/s.
// Dedup/sort (>=68us preprocess), bf16/fp8 table conversion (>=43us/launch),
// and L3 phasing all cost more than they can save under that cap. The direct
// kernel is at the ceiling; this round only trims lines:
//  - zero[] never read (all zeros; bias_w is a single element)
//  - user_w gathers are nontemporal (512 MB of zero-reuse lines stop
//    evicting item_w/index lines from L2/L3)
//  - 4x unrolled grid-stride loop for memory-level parallelism
//
// Round-6 fix: __builtin_nontemporal_load requires a clang ext_vector pointer,
// not HIP_vector_type<float,4>*.

#define EMB_DIM 64

typedef float f4 __attribute__((ext_vector_type(4)));

__global__ __launch_bounds__(256) void sfc_fwd(
    const int* __restrict__ user, const int* __restrict__ item,
    const int* __restrict__ freq, const int* __restrict__ idx_emb,
    const float* __restrict__ bias_w, const float* __restrict__ user_w,
    const float* __restrict__ item_w, const float* __restrict__ freq_w,
    float* __restrict__ out, int B)
{
    const int group_in_block = threadIdx.x >> 4;   // 16 groups of 16 lanes
    const int lane = threadIdx.x & 15;
    const int stride = (gridDim.x * blockDim.x) >> 4;
    const int start = blockIdx.x * 16 + group_in_block;
    const float bias0 = bias_w[0];

    int s = start;
    for (; s + 3 * stride < B; s += 4 * stride) {
        const int sa = s, sb = s + stride, sc = s + 2 * stride, sd = s + 3 * stride;

        const int ua = user[sa], ub = user[sb], uc = user[sc], ud = user[sd];
        const int ia = item[sa], ib = item[sb], ic = item[sc], id_ = item[sd];

        // user rows: nontemporal (no reuse); item rows: cached (21x reuse)
        const f4 uva = __builtin_nontemporal_load(
            reinterpret_cast<const f4*>(user_w + (size_t)ua * EMB_DIM + lane * 4));
        const f4 uvb = __builtin_nontemporal_load(
            reinterpret_cast<const f4*>(user_w + (size_t)ub * EMB_DIM + lane * 4));
        const f4 uvc = __builtin_nontemporal_load(
            reinterpret_cast<const f4*>(user_w + (size_t)uc * EMB_DIM + lane * 4));
        const f4 uvd = __builtin_nontemporal_load(
            reinterpret_cast<const f4*>(user_w + (size_t)ud * EMB_DIM + lane * 4));
        const f4 iva = *reinterpret_cast<const f4*>(item_w + (size_t)ia * EMB_DIM + lane * 4);
        const f4 ivb = *reinterpret_cast<const f4*>(item_w + (size_t)ib * EMB_DIM + lane * 4);
        const f4 ivc = *reinterpret_cast<const f4*>(item_w + (size_t)ic * EMB_DIM + lane * 4);
        const f4 ivd = *reinterpret_cast<const f4*>(item_w + (size_t)id_ * EMB_DIM + lane * 4);

        float da = uva.x * iva.x + uva.y * iva.y + uva.z * iva.z + uva.w * iva.w;
        float db = uvb.x * ivb.x + uvb.y * ivb.y + uvb.z * ivb.z + uvb.w * ivb.w;
        float dc = uvc.x * ivc.x + uvc.y * ivc.y + uvc.z * ivc.z + uvc.w * ivc.w;
        float dd = uvd.x * ivd.x + uvd.y * ivd.y + uvd.z * ivd.z + uvd.w * ivd.w;

        da += __shfl_xor(da, 1); da += __shfl_xor(da, 2); da += __shfl_xor(da, 4); da += __shfl_xor(da, 8);
        db += __shfl_xor(db, 1); db += __shfl_xor(db, 2); db += __shfl_xor(db, 4); db += __shfl_xor(db, 8);
        dc += __shfl_xor(dc, 1); dc += __shfl_xor(dc, 2); dc += __shfl_xor(dc, 4); dc += __shfl_xor(dc, 8);
        dd += __shfl_xor(dd, 1); dd += __shfl_xor(dd, 2); dd += __shfl_xor(dd, 4); dd += __shfl_xor(dd, 8);

        if (lane == 0) {
            out[sa] = bias0 + da + freq_w[idx_emb[sa] * 32 + freq[sa]];
            out[sb] = bias0 + db + freq_w[idx_emb[sb] * 32 + freq[sb]];
            out[sc] = bias0 + dc + freq_w[idx_emb[sc] * 32 + freq[sc]];
            out[sd] = bias0 + dd + freq_w[idx_emb[sd] * 32 + freq[sd]];
        }
    }
    for (; s < B; s += stride) {
        const f4 uv = __builtin_nontemporal_load(
            reinterpret_cast<const f4*>(user_w + (size_t)user[s] * EMB_DIM + lane * 4));
        const f4 vv = *reinterpret_cast<const f4*>(item_w + (size_t)item[s] * EMB_DIM + lane * 4);
        float d = uv.x * vv.x + uv.y * vv.y + uv.z * vv.z + uv.w * vv.w;
        d += __shfl_xor(d, 1); d += __shfl_xor(d, 2); d += __shfl_xor(d, 4); d += __shfl_xor(d, 8);
        if (lane == 0)
            out[s] = bias0 + d + freq_w[idx_emb[s] * 32 + freq[s]];
    }
}

extern "C" void kernel_launch(void* const* d_in, const int* in_sizes, int n_in,
                              void* d_out, int out_size, void* d_ws, size_t ws_size,
                              hipStream_t stream) {
    const int B = in_sizes[0];
    const int*   user    = (const int*)d_in[0];
    const int*   item    = (const int*)d_in[1];
    const int*   freq    = (const int*)d_in[2];
    const int*   idx_emb = (const int*)d_in[3];
    // d_in[4] (zero) intentionally unused: all zeros, bias_w has one element.
    const float* bias_w  = (const float*)d_in[5];
    const float* user_w  = (const float*)d_in[6];
    const float* item_w  = (const float*)d_in[7];
    const float* freq_w  = (const float*)d_in[8];
    float* out = (float*)d_out;

    // 2048 blocks x 256 threads -> 8 blocks/CU (32 waves/CU, occupancy-max).
    sfc_fwd<<<2048, 256, 0, stream>>>(user, item, freq, idx_emb,
                                      bias_w, user_w, item_w, freq_w, out, B);
}